// Round 7
// baseline (42.032 us; speedup 1.0000x reference)
//
#include <hip/hip_runtime.h>

// LePE window attention, 32x32x16 bf16 MFMA, P kept in registers via
// v_permlane32_swap_b32 (no P LDS buffer), LePE conv fused in-register.
// R6 fix: conv halo widened to [tok0+4*h5-12, +40) — R5's [-8,+40) window
// missed token offset -9 for h5=1 lanes (r=0, dy=-1, dx=-1), and the idx<0
// clamp silently substituted a wrong tap (absmax 1.19 == wreg[0]*dV tail).
// B=8, H=W=64, C=128, HEADS=4, HD=32; windows 64x8 -> 64 windows x 512 tokens.
// Block = (window, head, q-half): 512 blocks x 512 threads, 8 waves x 32 q rows.
// LDS = K[512][36] + V^T[32][524] bf16 = 70.4 KB -> 2 blocks/CU (16 waves).

namespace {
constexpr int Bn   = 8;
constexpr int Ww   = 64;
constexpr int Cc   = 128;
constexpr int HD   = 32;
constexpr int WSP  = 8;
constexpr int NTOK = 512;
constexpr int LL   = 64 * 64;
// 32^-0.5 * log2(e): exp(s) == exp2(s') with scale folded into Q
constexpr float SCALE_L2E = 0.17677669529663687f * 1.4426950408889634f;
constexpr int KPAD = 36;   // K row stride in shorts
constexpr int VPAD = 524;  // V^T row stride in shorts
}

typedef __bf16 bf16x8 __attribute__((ext_vector_type(8)));
typedef float  f32x16 __attribute__((ext_vector_type(16)));
typedef unsigned int uint32x4 __attribute__((ext_vector_type(4)));

__device__ inline unsigned int pack2bf(float x, float y) {   // round-half-up
    unsigned int ux = __builtin_bit_cast(unsigned int, x);
    unsigned int uy = __builtin_bit_cast(unsigned int, y);
    return ((ux + 0x8000u) >> 16) | ((uy + 0x8000u) & 0xFFFF0000u);
}
__device__ inline short bf1(float x) {
    unsigned int ux = __builtin_bit_cast(unsigned int, x);
    return (short)((ux + 0x8000u) >> 16);
}

__global__ __launch_bounds__(512, 4) void attn_kernel(const float* __restrict__ qkv,
                                                      const float* __restrict__ cw,
                                                      const float* __restrict__ cb,
                                                      float* __restrict__ out) {
    const int blk = blockIdx.x;          // 0..511
    const int w   = blk >> 3;            // window 0..63
    const int h   = (blk >> 1) & 3;      // head
    const int qh  = blk & 1;             // q half (256 rows)
    const int b   = w >> 3;
    const int wb  = w & 7;
    const int tid = threadIdx.x;
    const int wv  = tid >> 6;            // wave 0..7 -> 32 q rows each
    const int lane = tid & 63;
    const int l31 = lane & 31;
    const int h5  = lane >> 5;

    const float* qp = qkv;
    const float* kp = qkv + (size_t)Bn * LL * Cc;
    const float* vp = qkv + (size_t)2 * Bn * LL * Cc;

    __shared__ short K_lds[NTOK][KPAD];
    __shared__ short VT_lds[HD][VPAD];

    // ---- Q fragments: q tok = qh*256 + wv*32 + l31, d = dc*16 + h5*8 + e ----
    const int qtok = qh * 256 + wv * 32 + l31;
    const int qlqi = (qtok >> 3) * Ww + wb * WSP + (qtok & 7);
    bf16x8 qf[2];
    {
        const float* p = qp + ((size_t)b * LL + qlqi) * Cc + h * HD + h5 * 8;
#pragma unroll
        for (int dc = 0; dc < 2; ++dc) {
            float4 a = *reinterpret_cast<const float4*>(p + dc * 16);
            float4 c = *reinterpret_cast<const float4*>(p + dc * 16 + 4);
            uint32x4 u;
            u.x = pack2bf(a.x * SCALE_L2E, a.y * SCALE_L2E);
            u.y = pack2bf(a.z * SCALE_L2E, a.w * SCALE_L2E);
            u.z = pack2bf(c.x * SCALE_L2E, c.y * SCALE_L2E);
            u.w = pack2bf(c.z * SCALE_L2E, c.w * SCALE_L2E);
            qf[dc] = __builtin_bit_cast(bf16x8, u);
        }
    }

    // ---- stage K and V^T (bf16) ----
    for (int i = tid; i < NTOK * 8; i += 512) {
        const int tok = i >> 3, j = i & 7;
        const int lqi = (tok >> 3) * Ww + wb * WSP + (tok & 7);
        const size_t base = ((size_t)b * LL + lqi) * Cc + h * HD + j * 4;
        float4 kv = *reinterpret_cast<const float4*>(kp + base);
        uint2 pk;
        pk.x = pack2bf(kv.x, kv.y);
        pk.y = pack2bf(kv.z, kv.w);
        *reinterpret_cast<uint2*>(&K_lds[tok][j * 4]) = pk;
        float4 vv = *reinterpret_cast<const float4*>(vp + base);
        VT_lds[j * 4 + 0][tok] = bf1(vv.x);
        VT_lds[j * 4 + 1][tok] = bf1(vv.y);
        VT_lds[j * 4 + 2][tok] = bf1(vv.z);
        VT_lds[j * 4 + 3][tok] = bf1(vv.w);
    }
    __syncthreads();   // the only barrier

    f32x16 acc = (f32x16)(0.f);
    float lsum = 0.f;
    const f32x16 z16 = (f32x16)(0.f);

    // ---- main loop: 16 tiles of 32 keys, barrier-free ----
    for (int kt = 0; kt < 16; ++kt) {
        const int krow = kt * 32 + l31;
        // A operand of S^T = K*Q^T: K[k=krow][d = dc*16 + h5*8 .. +7]
        bf16x8 kf[2];
#pragma unroll
        for (int dc = 0; dc < 2; ++dc) {
            const uint2 a0 = *reinterpret_cast<const uint2*>(&K_lds[krow][dc * 16 + h5 * 8]);
            const uint2 a1 = *reinterpret_cast<const uint2*>(&K_lds[krow][dc * 16 + h5 * 8 + 4]);
            uint32x4 u; u.x = a0.x; u.y = a0.y; u.z = a1.x; u.w = a1.y;
            kf[dc] = __builtin_bit_cast(bf16x8, u);
        }
        f32x16 s = z16;
        s = __builtin_amdgcn_mfma_f32_32x32x16_bf16(kf[0], qf[0], s, 0, 0, 0);
        s = __builtin_amdgcn_mfma_f32_32x32x16_bf16(kf[1], qf[1], s, 0, 0, 0);
        // lane holds S^T[k][q=l31], k = (reg&3) + 8*(reg>>2) + 4*h5 + kt*32

        float pe[16];
#pragma unroll
        for (int i = 0; i < 16; ++i) pe[i] = exp2f(s[i]);
        {
            float t0 = 0.f, t1 = 0.f;
#pragma unroll
            for (int i = 0; i < 8; ++i) { t0 += pe[2 * i]; t1 += pe[2 * i + 1]; }
            lsum += t0 + t1;
        }
        unsigned dw[8];
#pragma unroll
        for (int i = 0; i < 8; ++i) dw[i] = pack2bf(pe[2 * i], pe[2 * i + 1]);

        // PV: per 16-key window kw, redistribute P across the h5 halves with
        // 2x v_permlane32_swap_b32 (vdst_hi <-> vsrc_lo), then one MFMA.
#pragma unroll
        for (int kw = 0; kw < 2; ++kw) {
            unsigned a0 = dw[4 * kw + 0], b0 = dw[4 * kw + 2];
            unsigned a1 = dw[4 * kw + 1], b1 = dw[4 * kw + 3];
            asm("v_permlane32_swap_b32 %0, %1" : "+v"(a0), "+v"(b0));
            asm("v_permlane32_swap_b32 %0, %1" : "+v"(a1), "+v"(b1));
            uint32x4 pu; pu.x = a0; pu.y = a1; pu.z = b0; pu.w = b1;
            // B operand: V[k = kt*32 + kw*16 + h5*8 + e][d = l31] from V^T rows
            const int kcol = kt * 32 + kw * 16 + h5 * 8;
            const uint2 v0 = *reinterpret_cast<const uint2*>(&VT_lds[l31][kcol]);
            const uint2 v1 = *reinterpret_cast<const uint2*>(&VT_lds[l31][kcol + 4]);
            uint32x4 vu; vu.x = v0.x; vu.y = v0.y; vu.z = v1.x; vu.w = v1.y;
            acc = __builtin_amdgcn_mfma_f32_32x32x16_bf16(
                __builtin_bit_cast(bf16x8, pu), __builtin_bit_cast(bf16x8, vu), acc, 0, 0, 0);
        }
    }

    // ---- softmax denominator: other k-half lives in the partner lane ----
    lsum += __shfl_xor(lsum, 32);
    const float inv = 1.f / lsum;

    // ---- LePE conv setup: this lane owns channel d = l31 of head h ----
    const int ch = h * HD + l31;
    float wreg[9];
#pragma unroll
    for (int wi = 0; wi < 9; ++wi) wreg[wi] = cw[ch * 9 + wi];
    const float bias = cb[ch];

    const int tok0 = qh * 256 + wv * 32;
    // V row segment toks [tok0 + 4*h5 - 12, +40): covers all consumed taps
    // (needed range rel. tok0+4h5 is [-9, +36]); clamped chunk slots are
    // only tokens <0 / >=512, all rowok-guarded.
    float vseg[52];
    {
        const int segbase = tok0 + 4 * h5 - 12;
#pragma unroll
        for (int c2 = 0; c2 < 13; ++c2) {
            int t = segbase + 4 * c2;
            t = t < 0 ? 0 : (t > NTOK - 4 ? NTOK - 4 : t);
            const uint2 u = *reinterpret_cast<const uint2*>(&VT_lds[l31][t]);
            vseg[c2 * 4 + 0] = __builtin_bit_cast(float, u.x << 16);
            vseg[c2 * 4 + 1] = __builtin_bit_cast(float, u.x & 0xFFFF0000u);
            vseg[c2 * 4 + 2] = __builtin_bit_cast(float, u.y << 16);
            vseg[c2 * 4 + 3] = __builtin_bit_cast(float, u.y & 0xFFFF0000u);
        }
    }

    // ---- epilogue: normalize + conv + store, per accumulator element ----
#pragma unroll
    for (int r = 0; r < 16; ++r) {
        const int c_r = (r & 3) + 8 * (r >> 2);           // q row offset (compile-time)
        const float iv = __shfl(inv, c_r + 4 * h5);       // q_r's denominator
        const int tok = tok0 + c_r + 4 * h5;
        float cv = bias;
#pragma unroll
        for (int dy = -1; dy <= 1; ++dy) {
            const bool rowok = (unsigned)(tok + dy * 8) < (unsigned)NTOK;
#pragma unroll
            for (int dx = -1; dx <= 1; ++dx) {
                const int idx = c_r + 12 + dy * 8 + dx;   // compile-time, in [3,48]
                bool ok = rowok;
                if (dx == -1) ok = ok && (((r & 3) != 0) || (h5 != 0));  // wc > 0
                if (dx == +1) ok = ok && (((r & 3) != 3) || (h5 == 0));  // wc < 7
                cv += ok ? wreg[(dy + 1) * 3 + (dx + 1)] * vseg[idx] : 0.f;
            }
        }
        const int lqi = (tok >> 3) * Ww + wb * WSP + (tok & 7);
        out[((size_t)b * LL + lqi) * Cc + ch] = acc[r] * iv + cv;
    }
}

extern "C" void kernel_launch(void* const* d_in, const int* in_sizes, int n_in,
                              void* d_out, int out_size, void* d_ws, size_t ws_size,
                              hipStream_t stream) {
    const float* qkv = (const float*)d_in[0];
    const float* cw  = (const float*)d_in[1];
    const float* cb  = (const float*)d_in[2];
    float* out = (float*)d_out;

    attn_kernel<<<512, 512, 0, stream>>>(qkv, cw, cb, out);
}

// Round 8
// 38.474 us; speedup vs baseline: 1.0925x; 1.0925x over previous
//
#include <hip/hip_runtime.h>

// LePE window attention, 32x32x16 bf16 MFMA, reg-P via v_permlane32_swap_b32.
// R7: 256 blocks x 1024 threads (16 waves) — K/V staged ONCE per (window,head);
// conv halo kept PACKED (26 uints) to kill the R6 vseg[52] register spill.
// B=8, H=W=64, C=128, HEADS=4, HD=32; windows 64x8 -> 64 windows x 512 tokens.
// LDS = K[512][36] + V^T[32][524] bf16 = 68.75 KB -> 1 block/CU, 16 waves.

namespace {
constexpr int Bn   = 8;
constexpr int Ww   = 64;
constexpr int Cc   = 128;
constexpr int HD   = 32;
constexpr int WSP  = 8;
constexpr int NTOK = 512;
constexpr int LL   = 64 * 64;
// 32^-0.5 * log2(e): exp(s) == exp2(s') with scale folded into Q
constexpr float SCALE_L2E = 0.17677669529663687f * 1.4426950408889634f;
constexpr int KPAD = 36;   // K row stride in shorts
constexpr int VPAD = 524;  // V^T row stride in shorts (1048 B, 8B-aligned rows)
}

typedef __bf16 bf16x8 __attribute__((ext_vector_type(8)));
typedef float  f32x16 __attribute__((ext_vector_type(16)));
typedef unsigned int uint32x4 __attribute__((ext_vector_type(4)));

__device__ inline unsigned int pack2bf(float x, float y) {   // round-half-up
    unsigned int ux = __builtin_bit_cast(unsigned int, x);
    unsigned int uy = __builtin_bit_cast(unsigned int, y);
    return ((ux + 0x8000u) >> 16) | ((uy + 0x8000u) & 0xFFFF0000u);
}

__global__ __launch_bounds__(1024, 4) void attn_kernel(const float* __restrict__ qkv,
                                                       const float* __restrict__ cw,
                                                       const float* __restrict__ cb,
                                                       float* __restrict__ out) {
    const int blk = blockIdx.x;          // 0..255
    const int w   = blk >> 2;            // window 0..63
    const int h   = blk & 3;             // head
    const int b   = w >> 3;
    const int wb  = w & 7;
    const int tid = threadIdx.x;         // 0..1023
    const int wv  = tid >> 6;            // wave 0..15 -> 32 q rows each
    const int lane = tid & 63;
    const int l31 = lane & 31;
    const int h5  = lane >> 5;

    const float* qp = qkv;
    const float* kp = qkv + (size_t)Bn * LL * Cc;
    const float* vp = qkv + (size_t)2 * Bn * LL * Cc;

    __shared__ short K_lds[NTOK][KPAD];
    __shared__ short VT_lds[HD][VPAD];

    // ---- Q fragments: q tok = wv*32 + l31, d = dc*16 + h5*8 + e ----
    const int qtok = wv * 32 + l31;
    const int qlqi = (qtok >> 3) * Ww + wb * WSP + (qtok & 7);
    bf16x8 qf[2];
    {
        const float* p = qp + ((size_t)b * LL + qlqi) * Cc + h * HD + h5 * 8;
#pragma unroll
        for (int dc = 0; dc < 2; ++dc) {
            float4 a = *reinterpret_cast<const float4*>(p + dc * 16);
            float4 c = *reinterpret_cast<const float4*>(p + dc * 16 + 4);
            uint32x4 u;
            u.x = pack2bf(a.x * SCALE_L2E, a.y * SCALE_L2E);
            u.y = pack2bf(a.z * SCALE_L2E, a.w * SCALE_L2E);
            u.z = pack2bf(c.x * SCALE_L2E, c.y * SCALE_L2E);
            u.w = pack2bf(c.z * SCALE_L2E, c.w * SCALE_L2E);
            qf[dc] = __builtin_bit_cast(bf16x8, u);
        }
    }

    // ---- stage K and V^T (bf16), token-pair scheme: 2048 items / 1024 thr ----
    for (int i = tid; i < (NTOK / 2) * 8; i += 1024) {
        const int tp = i >> 3, j = i & 7;      // token pair, d-group
        const int t0 = tp * 2, t1 = t0 + 1;
        const int lqi0 = (t0 >> 3) * Ww + wb * WSP + (t0 & 7);
        const int lqi1 = (t1 >> 3) * Ww + wb * WSP + (t1 & 7);
        const size_t b0 = ((size_t)b * LL + lqi0) * Cc + h * HD + j * 4;
        const size_t b1 = ((size_t)b * LL + lqi1) * Cc + h * HD + j * 4;
        const float4 k0 = *reinterpret_cast<const float4*>(kp + b0);
        const float4 k1 = *reinterpret_cast<const float4*>(kp + b1);
        uint2 pk0, pk1;
        pk0.x = pack2bf(k0.x, k0.y);  pk0.y = pack2bf(k0.z, k0.w);
        pk1.x = pack2bf(k1.x, k1.y);  pk1.y = pack2bf(k1.z, k1.w);
        *reinterpret_cast<uint2*>(&K_lds[t0][j * 4]) = pk0;
        *reinterpret_cast<uint2*>(&K_lds[t1][j * 4]) = pk1;
        const float4 v0 = *reinterpret_cast<const float4*>(vp + b0);
        const float4 v1 = *reinterpret_cast<const float4*>(vp + b1);
        *reinterpret_cast<unsigned*>(&VT_lds[j * 4 + 0][t0]) = pack2bf(v0.x, v1.x);
        *reinterpret_cast<unsigned*>(&VT_lds[j * 4 + 1][t0]) = pack2bf(v0.y, v1.y);
        *reinterpret_cast<unsigned*>(&VT_lds[j * 4 + 2][t0]) = pack2bf(v0.z, v1.z);
        *reinterpret_cast<unsigned*>(&VT_lds[j * 4 + 3][t0]) = pack2bf(v0.w, v1.w);
    }
    __syncthreads();   // the only barrier

    f32x16 acc = (f32x16)(0.f);
    float lsum = 0.f;
    const f32x16 z16 = (f32x16)(0.f);

    // ---- main loop: 16 tiles of 32 keys, barrier-free ----
    for (int kt = 0; kt < 16; ++kt) {
        const int krow = kt * 32 + l31;
        bf16x8 kf[2];
#pragma unroll
        for (int dc = 0; dc < 2; ++dc) {
            const uint2 a0 = *reinterpret_cast<const uint2*>(&K_lds[krow][dc * 16 + h5 * 8]);
            const uint2 a1 = *reinterpret_cast<const uint2*>(&K_lds[krow][dc * 16 + h5 * 8 + 4]);
            uint32x4 u; u.x = a0.x; u.y = a0.y; u.z = a1.x; u.w = a1.y;
            kf[dc] = __builtin_bit_cast(bf16x8, u);
        }
        f32x16 s = z16;
        s = __builtin_amdgcn_mfma_f32_32x32x16_bf16(kf[0], qf[0], s, 0, 0, 0);
        s = __builtin_amdgcn_mfma_f32_32x32x16_bf16(kf[1], qf[1], s, 0, 0, 0);
        // lane holds S^T[k][q=l31], k = (reg&3) + 8*(reg>>2) + 4*h5 + kt*32

        float pe[16];
#pragma unroll
        for (int i = 0; i < 16; ++i) pe[i] = exp2f(s[i]);
        {
            float t0 = 0.f, t1 = 0.f;
#pragma unroll
            for (int i = 0; i < 8; ++i) { t0 += pe[2 * i]; t1 += pe[2 * i + 1]; }
            lsum += t0 + t1;
        }
        unsigned dw[8];
#pragma unroll
        for (int i = 0; i < 8; ++i) dw[i] = pack2bf(pe[2 * i], pe[2 * i + 1]);

        // PV: per 16-key window kw, redistribute P across the h5 halves with
        // 2x v_permlane32_swap_b32 (vdst_hi <-> vsrc_lo), then one MFMA.
#pragma unroll
        for (int kw = 0; kw < 2; ++kw) {
            unsigned a0 = dw[4 * kw + 0], b0 = dw[4 * kw + 2];
            unsigned a1 = dw[4 * kw + 1], b1 = dw[4 * kw + 3];
            asm("v_permlane32_swap_b32 %0, %1" : "+v"(a0), "+v"(b0));
            asm("v_permlane32_swap_b32 %0, %1" : "+v"(a1), "+v"(b1));
            uint32x4 pu; pu.x = a0; pu.y = a1; pu.z = b0; pu.w = b1;
            const int kcol = kt * 32 + kw * 16 + h5 * 8;
            const uint2 v0 = *reinterpret_cast<const uint2*>(&VT_lds[l31][kcol]);
            const uint2 v1 = *reinterpret_cast<const uint2*>(&VT_lds[l31][kcol + 4]);
            uint32x4 vu; vu.x = v0.x; vu.y = v0.y; vu.z = v1.x; vu.w = v1.y;
            acc = __builtin_amdgcn_mfma_f32_32x32x16_bf16(
                __builtin_bit_cast(bf16x8, pu), __builtin_bit_cast(bf16x8, vu), acc, 0, 0, 0);
        }
    }

    // ---- softmax denominator: other k-half lives in the partner lane ----
    lsum += __shfl_xor(lsum, 32);
    const float inv = 1.f / lsum;

    // ---- LePE conv: lane owns channel d = l31 of head h ----
    const int ch = h * HD + l31;
    float wreg[9];
#pragma unroll
    for (int wi = 0; wi < 9; ++wi) wreg[wi] = cw[ch * 9 + wi];
    const float bias = cb[ch];

    const int tok0 = wv * 32;
    // Packed V halo: 52 bf16 toks [tok0 + 4*h5 - 12, +40) as 26 uints.
    // Needed tap range rel. tok0+4h5 is [-9,+36]; clamped chunk slots are only
    // tokens <0 / >=512, all rowok-guarded below.
    unsigned hw[26];
    {
        const int segbase = tok0 + 4 * h5 - 12;
#pragma unroll
        for (int c2 = 0; c2 < 13; ++c2) {
            int t = segbase + 4 * c2;
            t = t < 0 ? 0 : (t > NTOK - 4 ? NTOK - 4 : t);
            const uint2 u = *reinterpret_cast<const uint2*>(&VT_lds[l31][t]);
            hw[c2 * 2 + 0] = u.x;
            hw[c2 * 2 + 1] = u.y;
        }
    }

    // ---- epilogue: normalize + conv + store, per accumulator element ----
#pragma unroll
    for (int r = 0; r < 16; ++r) {
        const int c_r = (r & 3) + 8 * (r >> 2);           // q row offset (compile-time)
        const float iv = __shfl(inv, c_r + 4 * h5);       // q_r's denominator
        const int tok = tok0 + c_r + 4 * h5;
        float cv = bias;
#pragma unroll
        for (int dy = -1; dy <= 1; ++dy) {
            const bool rowok = (unsigned)(tok + dy * 8) < (unsigned)NTOK;
#pragma unroll
            for (int dx = -1; dx <= 1; ++dx) {
                const int idx = c_r + 12 + dy * 8 + dx;   // compile-time, in [3,48]
                const unsigned word = hw[idx >> 1];
                const float tap = __builtin_bit_cast(float,
                    (idx & 1) ? (word & 0xFFFF0000u) : (word << 16));
                bool ok = rowok;
                if (dx == -1) ok = ok && (((r & 3) != 0) || (h5 != 0));  // wc > 0
                if (dx == +1) ok = ok && (((r & 3) != 3) || (h5 == 0));  // wc < 7
                cv += ok ? wreg[(dy + 1) * 3 + (dx + 1)] * tap : 0.f;
            }
        }
        const int lqi = (tok >> 3) * Ww + wb * WSP + (tok & 7);
        out[((size_t)b * LL + lqi) * Cc + ch] = acc[r] * iv + cv;
    }
}

extern "C" void kernel_launch(void* const* d_in, const int* in_sizes, int n_in,
                              void* d_out, int out_size, void* d_ws, size_t ws_size,
                              hipStream_t stream) {
    const float* qkv = (const float*)d_in[0];
    const float* cw  = (const float*)d_in[1];
    const float* cb  = (const float*)d_in[2];
    float* out = (float*)d_out;

    attn_kernel<<<256, 1024, 0, stream>>>(qkv, cw, cb, out);
}

// Round 9
// 36.608 us; speedup vs baseline: 1.1481x; 1.0510x over previous
//
#include <hip/hip_runtime.h>

// LePE window attention, 32x32x16 bf16 MFMA, reg-P via v_permlane32_swap_b32.
// R9: all f32->bf16 packing via v_cvt_pk_bf16_f32 (1 instr vs ~5 emulated),
// explicit kf/vu prefetch registers to break the per-kt serial chain,
// s_setprio around MFMA clusters. Structure unchanged from R8:
// 256 blocks x 1024 threads (16 waves), K/V staged once per (window,head).
// LDS = K[512][36] + V^T[32][524] bf16 = 69 KB.

namespace {
constexpr int Bn   = 8;
constexpr int Ww   = 64;
constexpr int Cc   = 128;
constexpr int HD   = 32;
constexpr int WSP  = 8;
constexpr int NTOK = 512;
constexpr int LL   = 64 * 64;
// 32^-0.5 * log2(e): exp(s) == exp2(s') with scale folded into Q
constexpr float SCALE_L2E = 0.17677669529663687f * 1.4426950408889634f;
constexpr int KPAD = 36;   // K row stride in shorts
constexpr int VPAD = 524;  // V^T row stride in shorts
}

typedef __bf16 bf16x8 __attribute__((ext_vector_type(8)));
typedef float  f32x16 __attribute__((ext_vector_type(16)));
typedef unsigned int uint32x4 __attribute__((ext_vector_type(4)));

// dst.lo = bf16(x), dst.hi = bf16(y) — single VALU op (RNE)
__device__ inline unsigned cvtpk(float x, float y) {
    unsigned r;
    asm("v_cvt_pk_bf16_f32 %0, %1, %2" : "=v"(r) : "v"(x), "v"(y));
    return r;
}

__global__ __launch_bounds__(1024, 4) void attn_kernel(const float* __restrict__ qkv,
                                                       const float* __restrict__ cw,
                                                       const float* __restrict__ cb,
                                                       float* __restrict__ out) {
    const int blk = blockIdx.x;          // 0..255
    const int w   = blk >> 2;            // window 0..63
    const int h   = blk & 3;             // head
    const int b   = w >> 3;
    const int wb  = w & 7;
    const int tid = threadIdx.x;         // 0..1023
    const int wv  = tid >> 6;            // wave 0..15 -> 32 q rows each
    const int lane = tid & 63;
    const int l31 = lane & 31;
    const int h5  = lane >> 5;

    const float* qp = qkv;
    const float* kp = qkv + (size_t)Bn * LL * Cc;
    const float* vp = qkv + (size_t)2 * Bn * LL * Cc;

    __shared__ short K_lds[NTOK][KPAD];
    __shared__ short VT_lds[HD][VPAD];

    // ---- Q fragments: q tok = wv*32 + l31, d = dc*16 + h5*8 + e ----
    const int qtok = wv * 32 + l31;
    const int qlqi = (qtok >> 3) * Ww + wb * WSP + (qtok & 7);
    bf16x8 qf[2];
    {
        const float* p = qp + ((size_t)b * LL + qlqi) * Cc + h * HD + h5 * 8;
#pragma unroll
        for (int dc = 0; dc < 2; ++dc) {
            float4 a = *reinterpret_cast<const float4*>(p + dc * 16);
            float4 c = *reinterpret_cast<const float4*>(p + dc * 16 + 4);
            uint32x4 u;
            u.x = cvtpk(a.x * SCALE_L2E, a.y * SCALE_L2E);
            u.y = cvtpk(a.z * SCALE_L2E, a.w * SCALE_L2E);
            u.z = cvtpk(c.x * SCALE_L2E, c.y * SCALE_L2E);
            u.w = cvtpk(c.z * SCALE_L2E, c.w * SCALE_L2E);
            qf[dc] = __builtin_bit_cast(bf16x8, u);
        }
    }

    // ---- stage K and V^T (bf16), token-pair scheme: 2048 items / 1024 thr ----
    for (int i = tid; i < (NTOK / 2) * 8; i += 1024) {
        const int tp = i >> 3, j = i & 7;      // token pair, d-group
        const int t0 = tp * 2, t1 = t0 + 1;
        const int lqi0 = (t0 >> 3) * Ww + wb * WSP + (t0 & 7);  // lqi1 = lqi0+1
        const size_t b0 = ((size_t)b * LL + lqi0) * Cc + h * HD + j * 4;
        const float4 k0 = *reinterpret_cast<const float4*>(kp + b0);
        const float4 k1 = *reinterpret_cast<const float4*>(kp + b0 + Cc);
        uint2 pk0, pk1;
        pk0.x = cvtpk(k0.x, k0.y);  pk0.y = cvtpk(k0.z, k0.w);
        pk1.x = cvtpk(k1.x, k1.y);  pk1.y = cvtpk(k1.z, k1.w);
        *reinterpret_cast<uint2*>(&K_lds[t0][j * 4]) = pk0;
        *reinterpret_cast<uint2*>(&K_lds[t1][j * 4]) = pk1;
        const float4 v0 = *reinterpret_cast<const float4*>(vp + b0);
        const float4 v1 = *reinterpret_cast<const float4*>(vp + b0 + Cc);
        *reinterpret_cast<unsigned*>(&VT_lds[j * 4 + 0][t0]) = cvtpk(v0.x, v1.x);
        *reinterpret_cast<unsigned*>(&VT_lds[j * 4 + 1][t0]) = cvtpk(v0.y, v1.y);
        *reinterpret_cast<unsigned*>(&VT_lds[j * 4 + 2][t0]) = cvtpk(v0.z, v1.z);
        *reinterpret_cast<unsigned*>(&VT_lds[j * 4 + 3][t0]) = cvtpk(v0.w, v1.w);
    }
    __syncthreads();   // the only barrier

    f32x16 acc = (f32x16)(0.f);
    float lsum = 0.f;
    const f32x16 z16 = (f32x16)(0.f);

    auto load_kf = [&](int kt, bf16x8* kf) {
        const int krow = kt * 32 + l31;
#pragma unroll
        for (int dc = 0; dc < 2; ++dc) {
            const uint2 a0 = *reinterpret_cast<const uint2*>(&K_lds[krow][dc * 16 + h5 * 8]);
            const uint2 a1 = *reinterpret_cast<const uint2*>(&K_lds[krow][dc * 16 + h5 * 8 + 4]);
            uint32x4 u; u.x = a0.x; u.y = a0.y; u.z = a1.x; u.w = a1.y;
            kf[dc] = __builtin_bit_cast(bf16x8, u);
        }
    };

    bf16x8 kf[2];
    load_kf(0, kf);

    // ---- main loop: 16 tiles of 32 keys, barrier-free ----
    for (int kt = 0; kt < 16; ++kt) {
        __builtin_amdgcn_s_setprio(1);
        f32x16 s = z16;
        s = __builtin_amdgcn_mfma_f32_32x32x16_bf16(kf[0], qf[0], s, 0, 0, 0);
        s = __builtin_amdgcn_mfma_f32_32x32x16_bf16(kf[1], qf[1], s, 0, 0, 0);
        __builtin_amdgcn_s_setprio(0);
        // lane holds S^T[k][q=l31], k = (reg&3) + 8*(reg>>2) + 4*h5 + kt*32

        // prefetch next kf + this kt's V fragments while s is in flight
        bf16x8 kfn[2];
        load_kf((kt + 1) & 15, kfn);
        uint32x4 vu[2];
#pragma unroll
        for (int kw = 0; kw < 2; ++kw) {
            const int kcol = kt * 32 + kw * 16 + h5 * 8;
            const uint2 v0 = *reinterpret_cast<const uint2*>(&VT_lds[l31][kcol]);
            const uint2 v1 = *reinterpret_cast<const uint2*>(&VT_lds[l31][kcol + 4]);
            vu[kw].x = v0.x; vu[kw].y = v0.y; vu[kw].z = v1.x; vu[kw].w = v1.y;
        }

        float pe[16];
#pragma unroll
        for (int i = 0; i < 16; ++i) pe[i] = exp2f(s[i]);
        {
            float t0 = 0.f, t1 = 0.f;
#pragma unroll
            for (int i = 0; i < 8; ++i) { t0 += pe[2 * i]; t1 += pe[2 * i + 1]; }
            lsum += t0 + t1;
        }
        unsigned dw[8];
#pragma unroll
        for (int i = 0; i < 8; ++i) dw[i] = cvtpk(pe[2 * i], pe[2 * i + 1]);

        // PV: per 16-key window kw, redistribute P across the h5 halves with
        // 2x v_permlane32_swap_b32 (vdst_hi <-> vsrc_lo), then one MFMA.
#pragma unroll
        for (int kw = 0; kw < 2; ++kw) {
            unsigned a0 = dw[4 * kw + 0], b0 = dw[4 * kw + 2];
            unsigned a1 = dw[4 * kw + 1], b1 = dw[4 * kw + 3];
            asm("v_permlane32_swap_b32 %0, %1" : "+v"(a0), "+v"(b0));
            asm("v_permlane32_swap_b32 %0, %1" : "+v"(a1), "+v"(b1));
            uint32x4 pu; pu.x = a0; pu.y = a1; pu.z = b0; pu.w = b1;
            __builtin_amdgcn_s_setprio(1);
            acc = __builtin_amdgcn_mfma_f32_32x32x16_bf16(
                __builtin_bit_cast(bf16x8, pu), __builtin_bit_cast(bf16x8, vu[kw]),
                acc, 0, 0, 0);
            __builtin_amdgcn_s_setprio(0);
        }
        kf[0] = kfn[0];
        kf[1] = kfn[1];
    }

    // ---- softmax denominator: other k-half lives in the partner lane ----
    lsum += __shfl_xor(lsum, 32);
    const float inv = 1.f / lsum;

    // ---- LePE conv: lane owns channel d = l31 of head h ----
    const int ch = h * HD + l31;
    float wreg[9];
#pragma unroll
    for (int wi = 0; wi < 9; ++wi) wreg[wi] = cw[ch * 9 + wi];
    const float bias = cb[ch];

    const int tok0 = wv * 32;
    // Packed V halo: 52 bf16 toks [tok0 + 4*h5 - 12, +40) as 26 uints.
    // Needed tap range rel. tok0+4h5 is [-9,+36]; clamped chunk slots are only
    // tokens <0 / >=512, all rowok-guarded below.
    unsigned hw[26];
    {
        const int segbase = tok0 + 4 * h5 - 12;
#pragma unroll
        for (int c2 = 0; c2 < 13; ++c2) {
            int t = segbase + 4 * c2;
            t = t < 0 ? 0 : (t > NTOK - 4 ? NTOK - 4 : t);
            const uint2 u = *reinterpret_cast<const uint2*>(&VT_lds[l31][t]);
            hw[c2 * 2 + 0] = u.x;
            hw[c2 * 2 + 1] = u.y;
        }
    }

    // ---- epilogue: normalize + conv + store, per accumulator element ----
#pragma unroll
    for (int r = 0; r < 16; ++r) {
        const int c_r = (r & 3) + 8 * (r >> 2);           // q row offset (compile-time)
        const float iv = __shfl(inv, c_r + 4 * h5);       // q_r's denominator
        const int tok = tok0 + c_r + 4 * h5;
        float cv = bias;
#pragma unroll
        for (int dy = -1; dy <= 1; ++dy) {
            const bool rowok = (unsigned)(tok + dy * 8) < (unsigned)NTOK;
#pragma unroll
            for (int dx = -1; dx <= 1; ++dx) {
                const int idx = c_r + 12 + dy * 8 + dx;   // compile-time, in [3,48]
                const unsigned word = hw[idx >> 1];
                const float tap = __builtin_bit_cast(float,
                    (idx & 1) ? (word & 0xFFFF0000u) : (word << 16));
                bool ok = rowok;
                if (dx == -1) ok = ok && (((r & 3) != 0) || (h5 != 0));  // wc > 0
                if (dx == +1) ok = ok && (((r & 3) != 3) || (h5 == 0));  // wc < 7
                cv += ok ? wreg[(dy + 1) * 3 + (dx + 1)] * tap : 0.f;
            }
        }
        const int lqi = (tok >> 3) * Ww + wb * WSP + (tok & 7);
        out[((size_t)b * LL + lqi) * Cc + ch] = acc[r] * iv + cv;
    }
}

extern "C" void kernel_launch(void* const* d_in, const int* in_sizes, int n_in,
                              void* d_out, int out_size, void* d_ws, size_t ws_size,
                              hipStream_t stream) {
    const float* qkv = (const float*)d_in[0];
    const float* cw  = (const float*)d_in[1];
    const float* cb  = (const float*)d_in[2];
    float* out = (float*)d_out;

    attn_kernel<<<256, 1024, 0, stream>>>(qkv, cw, cb, out);
}

// Round 10
// 29.187 us; speedup vs baseline: 1.4401x; 1.2543x over previous
//
#include <hip/hip_runtime.h>

// LePE window attention, 32x32x16 bf16 MFMA, reg-P via v_permlane32_swap_b32.
// R10: raw v_exp_f32 (__builtin_amdgcn_exp2f) instead of OCML exp2f;
// KPAD 36->40 / VPAD 524->536 so kf and vu fragment loads are single
// 16B-aligned ds_read_b128 each (8 -> 4 LDS instrs per kt, no assembly movs).
// Structure unchanged: 256 blocks x 1024 threads (16 waves), K/V staged once.
// LDS = K[512][40] + V^T[32][536] bf16 = 73.5 KB.

namespace {
constexpr int Bn   = 8;
constexpr int Ww   = 64;
constexpr int Cc   = 128;
constexpr int HD   = 32;
constexpr int WSP  = 8;
constexpr int NTOK = 512;
constexpr int LL   = 64 * 64;
// 32^-0.5 * log2(e): exp(s) == exp2(s') with scale folded into Q
constexpr float SCALE_L2E = 0.17677669529663687f * 1.4426950408889634f;
constexpr int KPAD = 40;   // K row stride in shorts (80B rows -> 16B-aligned frags)
constexpr int VPAD = 536;  // V^T row stride in shorts (1072B rows -> 16B-aligned)
}

typedef __bf16 bf16x8 __attribute__((ext_vector_type(8)));
typedef float  f32x16 __attribute__((ext_vector_type(16)));
typedef unsigned int uint32x4 __attribute__((ext_vector_type(4)));

// dst.lo = bf16(x), dst.hi = bf16(y) — single VALU op (RNE)
__device__ inline unsigned cvtpk(float x, float y) {
    unsigned r;
    asm("v_cvt_pk_bf16_f32 %0, %1, %2" : "=v"(r) : "v"(x), "v"(y));
    return r;
}

__global__ __launch_bounds__(1024, 4) void attn_kernel(const float* __restrict__ qkv,
                                                       const float* __restrict__ cw,
                                                       const float* __restrict__ cb,
                                                       float* __restrict__ out) {
    const int blk = blockIdx.x;          // 0..255
    const int w   = blk >> 2;            // window 0..63
    const int h   = blk & 3;             // head
    const int b   = w >> 3;
    const int wb  = w & 7;
    const int tid = threadIdx.x;         // 0..1023
    const int wv  = tid >> 6;            // wave 0..15 -> 32 q rows each
    const int lane = tid & 63;
    const int l31 = lane & 31;
    const int h5  = lane >> 5;

    const float* qp = qkv;
    const float* kp = qkv + (size_t)Bn * LL * Cc;
    const float* vp = qkv + (size_t)2 * Bn * LL * Cc;

    __shared__ short K_lds[NTOK][KPAD];
    __shared__ short VT_lds[HD][VPAD];

    // ---- Q fragments: q tok = wv*32 + l31, d = dc*16 + h5*8 + e ----
    const int qtok = wv * 32 + l31;
    const int qlqi = (qtok >> 3) * Ww + wb * WSP + (qtok & 7);
    bf16x8 qf[2];
    {
        const float* p = qp + ((size_t)b * LL + qlqi) * Cc + h * HD + h5 * 8;
#pragma unroll
        for (int dc = 0; dc < 2; ++dc) {
            float4 a = *reinterpret_cast<const float4*>(p + dc * 16);
            float4 c = *reinterpret_cast<const float4*>(p + dc * 16 + 4);
            uint32x4 u;
            u.x = cvtpk(a.x * SCALE_L2E, a.y * SCALE_L2E);
            u.y = cvtpk(a.z * SCALE_L2E, a.w * SCALE_L2E);
            u.z = cvtpk(c.x * SCALE_L2E, c.y * SCALE_L2E);
            u.w = cvtpk(c.z * SCALE_L2E, c.w * SCALE_L2E);
            qf[dc] = __builtin_bit_cast(bf16x8, u);
        }
    }

    // ---- stage K and V^T (bf16), token-pair scheme: 2048 items / 1024 thr ----
    for (int i = tid; i < (NTOK / 2) * 8; i += 1024) {
        const int tp = i >> 3, j = i & 7;      // token pair, d-group
        const int t0 = tp * 2, t1 = t0 + 1;
        const int lqi0 = (t0 >> 3) * Ww + wb * WSP + (t0 & 7);  // lqi1 = lqi0+1
        const size_t b0 = ((size_t)b * LL + lqi0) * Cc + h * HD + j * 4;
        const float4 k0 = *reinterpret_cast<const float4*>(kp + b0);
        const float4 k1 = *reinterpret_cast<const float4*>(kp + b0 + Cc);
        uint2 pk0, pk1;
        pk0.x = cvtpk(k0.x, k0.y);  pk0.y = cvtpk(k0.z, k0.w);
        pk1.x = cvtpk(k1.x, k1.y);  pk1.y = cvtpk(k1.z, k1.w);
        *reinterpret_cast<uint2*>(&K_lds[t0][j * 4]) = pk0;
        *reinterpret_cast<uint2*>(&K_lds[t1][j * 4]) = pk1;
        const float4 v0 = *reinterpret_cast<const float4*>(vp + b0);
        const float4 v1 = *reinterpret_cast<const float4*>(vp + b0 + Cc);
        *reinterpret_cast<unsigned*>(&VT_lds[j * 4 + 0][t0]) = cvtpk(v0.x, v1.x);
        *reinterpret_cast<unsigned*>(&VT_lds[j * 4 + 1][t0]) = cvtpk(v0.y, v1.y);
        *reinterpret_cast<unsigned*>(&VT_lds[j * 4 + 2][t0]) = cvtpk(v0.z, v1.z);
        *reinterpret_cast<unsigned*>(&VT_lds[j * 4 + 3][t0]) = cvtpk(v0.w, v1.w);
    }
    __syncthreads();   // the only barrier

    f32x16 acc = (f32x16)(0.f);
    float lsum = 0.f;
    const f32x16 z16 = (f32x16)(0.f);

    auto load_kf = [&](int kt, bf16x8* kf) {
        const int krow = kt * 32 + l31;
#pragma unroll
        for (int dc = 0; dc < 2; ++dc)
            kf[dc] = __builtin_bit_cast(bf16x8,
                *reinterpret_cast<const uint32x4*>(&K_lds[krow][dc * 16 + h5 * 8]));
    };

    bf16x8 kf[2];
    load_kf(0, kf);

    // ---- main loop: 16 tiles of 32 keys, barrier-free ----
    for (int kt = 0; kt < 16; ++kt) {
        __builtin_amdgcn_s_setprio(1);
        f32x16 s = z16;
        s = __builtin_amdgcn_mfma_f32_32x32x16_bf16(kf[0], qf[0], s, 0, 0, 0);
        s = __builtin_amdgcn_mfma_f32_32x32x16_bf16(kf[1], qf[1], s, 0, 0, 0);
        __builtin_amdgcn_s_setprio(0);
        // lane holds S^T[k][q=l31], k = (reg&3) + 8*(reg>>2) + 4*h5 + kt*32

        // prefetch next kf + this kt's V fragments while s is in flight
        bf16x8 kfn[2];
        load_kf((kt + 1) & 15, kfn);
        uint32x4 vu[2];
#pragma unroll
        for (int kw = 0; kw < 2; ++kw) {
            const int kcol = kt * 32 + kw * 16 + h5 * 8;
            vu[kw] = *reinterpret_cast<const uint32x4*>(&VT_lds[l31][kcol]);
        }

        float pe[16];
#pragma unroll
        for (int i = 0; i < 16; ++i) pe[i] = __builtin_amdgcn_exp2f(s[i]);
        {
            float t0 = 0.f, t1 = 0.f;
#pragma unroll
            for (int i = 0; i < 8; ++i) { t0 += pe[2 * i]; t1 += pe[2 * i + 1]; }
            lsum += t0 + t1;
        }
        unsigned dw[8];
#pragma unroll
        for (int i = 0; i < 8; ++i) dw[i] = cvtpk(pe[2 * i], pe[2 * i + 1]);

        // PV: per 16-key window kw, redistribute P across the h5 halves with
        // 2x v_permlane32_swap_b32 (vdst_hi <-> vsrc_lo), then one MFMA.
#pragma unroll
        for (int kw = 0; kw < 2; ++kw) {
            unsigned a0 = dw[4 * kw + 0], b0 = dw[4 * kw + 2];
            unsigned a1 = dw[4 * kw + 1], b1 = dw[4 * kw + 3];
            asm("v_permlane32_swap_b32 %0, %1" : "+v"(a0), "+v"(b0));
            asm("v_permlane32_swap_b32 %0, %1" : "+v"(a1), "+v"(b1));
            uint32x4 pu; pu.x = a0; pu.y = a1; pu.z = b0; pu.w = b1;
            __builtin_amdgcn_s_setprio(1);
            acc = __builtin_amdgcn_mfma_f32_32x32x16_bf16(
                __builtin_bit_cast(bf16x8, pu), __builtin_bit_cast(bf16x8, vu[kw]),
                acc, 0, 0, 0);
            __builtin_amdgcn_s_setprio(0);
        }
        kf[0] = kfn[0];
        kf[1] = kfn[1];
    }

    // ---- softmax denominator: other k-half lives in the partner lane ----
    lsum += __shfl_xor(lsum, 32);
    const float inv = 1.f / lsum;

    // ---- LePE conv: lane owns channel d = l31 of head h ----
    const int ch = h * HD + l31;
    float wreg[9];
#pragma unroll
    for (int wi = 0; wi < 9; ++wi) wreg[wi] = cw[ch * 9 + wi];
    const float bias = cb[ch];

    const int tok0 = wv * 32;
    // Packed V halo: 52 bf16 toks [tok0 + 4*h5 - 12, +40) as 26 uints.
    // Needed tap range rel. tok0+4h5 is [-9,+36]; clamped chunk slots are only
    // tokens <0 / >=512, all rowok-guarded below.
    unsigned hw[26];
    {
        const int segbase = tok0 + 4 * h5 - 12;
#pragma unroll
        for (int c2 = 0; c2 < 13; ++c2) {
            int t = segbase + 4 * c2;
            t = t < 0 ? 0 : (t > NTOK - 4 ? NTOK - 4 : t);
            const uint2 u = *reinterpret_cast<const uint2*>(&VT_lds[l31][t]);
            hw[c2 * 2 + 0] = u.x;
            hw[c2 * 2 + 1] = u.y;
        }
    }

    // ---- epilogue: normalize + conv + store, per accumulator element ----
#pragma unroll
    for (int r = 0; r < 16; ++r) {
        const int c_r = (r & 3) + 8 * (r >> 2);           // q row offset (compile-time)
        const float iv = __shfl(inv, c_r + 4 * h5);       // q_r's denominator
        const int tok = tok0 + c_r + 4 * h5;
        float cv = bias;
#pragma unroll
        for (int dy = -1; dy <= 1; ++dy) {
            const bool rowok = (unsigned)(tok + dy * 8) < (unsigned)NTOK;
#pragma unroll
            for (int dx = -1; dx <= 1; ++dx) {
                const int idx = c_r + 12 + dy * 8 + dx;   // compile-time, in [3,48]
                const unsigned word = hw[idx >> 1];
                const float tap = __builtin_bit_cast(float,
                    (idx & 1) ? (word & 0xFFFF0000u) : (word << 16));
                bool ok = rowok;
                if (dx == -1) ok = ok && (((r & 3) != 0) || (h5 != 0));  // wc > 0
                if (dx == +1) ok = ok && (((r & 3) != 3) || (h5 == 0));  // wc < 7
                cv += ok ? wreg[(dy + 1) * 3 + (dx + 1)] * tap : 0.f;
            }
        }
        const int lqi = (tok >> 3) * Ww + wb * WSP + (tok & 7);
        out[((size_t)b * LL + lqi) * Cc + ch] = acc[r] * iv + cv;
    }
}

extern "C" void kernel_launch(void* const* d_in, const int* in_sizes, int n_in,
                              void* d_out, int out_size, void* d_ws, size_t ws_size,
                              hipStream_t stream) {
    const float* qkv = (const float*)d_in[0];
    const float* cw  = (const float*)d_in[1];
    const float* cb  = (const float*)d_in[2];
    float* out = (float*)d_out;

    attn_kernel<<<256, 1024, 0, stream>>>(qkv, cw, cb, out);
}